// Round 3
// baseline (629.846 us; speedup 1.0000x reference)
//
#include <hip/hip_runtime.h>
#include <stdint.h>

typedef unsigned short u16;
typedef unsigned int   u32;

#define WW 512
#define HH 512
#define BB 4
#define CC 32
#define EPSW 1e-3f

typedef __bf16 bf16x8 __attribute__((ext_vector_type(8)));
typedef short  s16x8  __attribute__((ext_vector_type(8)));

union FragU { s16x8 s; bf16x8 b; };

__device__ __forceinline__ int reflect512(int i) {
    i = (i < 0) ? -i : i;
    return (i >= WW) ? (2*WW - 2 - i) : i;
}

__device__ __forceinline__ u16 f2bf(float f) {
    u32 u = __float_as_uint(f);
    u32 r = (u + 0x7fffu + ((u >> 16) & 1u)) >> 16;
    return (u16)r;
}

// ---------------- horizontal pass: x (f32) -> ws u32[b][h][w][c] {g1,g2} ----
// grid (8 cchunks, 512 h, 4 b), block 256. Thread owns 2 consecutive w, 4 ch,
// both gaussians (shares the l+r symmetric sums).
__global__ __launch_bounds__(256, 4)
void hpass(const float* __restrict__ x, const float* __restrict__ sig,
           u32* __restrict__ ws)
{
    __shared__ float xs[4][576];   // i -> w = i-32 (reflect)
    const int t  = threadIdx.x;
    const int c0 = blockIdx.x * 4;
    const int h  = blockIdx.y;
    const int b  = blockIdx.z;

    #pragma unroll
    for (int c = 0; c < 4; ++c) {
        const float* src = x + ((size_t)((b*CC + c0 + c)*HH + h))*WW;
        for (int i = t; i < 576; i += 256)
            xs[c][i] = src[reflect512(i - 32)];
    }
    __syncthreads();

    const int w0 = t * 2;
    float2 sg = *(const float2*)(sig + ((size_t)(b*HH + h))*WW + w0);

    float m1[2], q1[2], wv1[2], S1[2], m2[2], q2[2], wv2[2], S2[2];
    #pragma unroll
    for (int p = 0; p < 2; ++p) {
        float s   = p ? sg.y : sg.x;
        float tt1 = -0.5f / (s*s);
        m1[p] = __expf(tt1);             q1[p] = m1[p]*m1[p];
        float tt2 = tt1 * 0.390625f;     // sigma2 = 1.6*sigma
        m2[p] = __expf(tt2);             q2[p] = m2[p]*m2[p];
        wv1[p] = 1.f; wv2[p] = 1.f; S1[p] = 0.f; S2[p] = 0.f;
    }

    float a1[4][2], a2[4][2];
    float2 Lhi[4], Rlo[4];
    #pragma unroll
    for (int c = 0; c < 4; ++c) {
        float2 Cq = *(const float2*)&xs[c][32 + w0];
        a1[c][0] = Cq.x; a1[c][1] = Cq.y;
        a2[c][0] = Cq.x; a2[c][1] = Cq.y;
        Lhi[c] = Cq; Rlo[c] = Cq;
    }

    #pragma unroll 1
    for (int kb = 0; kb < 15; ++kb) {      // taps k = 2kb+1, 2kb+2  (k=1..30)
        float tw1[2][2], tw2[2][2];        // [j][p]
        #pragma unroll
        for (int j = 0; j < 2; ++j)
            #pragma unroll
            for (int p = 0; p < 2; ++p) {
                wv1[p] *= m1[p]; m1[p] *= q1[p];
                float ta = (wv1[p] >= EPSW) ? wv1[p] : 0.f;
                tw1[j][p] = ta; S1[p] += ta;
                wv2[p] *= m2[p]; m2[p] *= q2[p];
                float tb = (wv2[p] >= EPSW) ? wv2[p] : 0.f;
                tw2[j][p] = tb; S2[p] += tb;
            }
        const int li = 32 + w0 - 2 - 2*kb;
        const int ri = 32 + w0 + 2 + 2*kb;
        #pragma unroll
        for (int c = 0; c < 4; ++c) {
            float2 Llo = *(const float2*)&xs[c][li];
            float2 Rhi = *(const float2*)&xs[c][ri];
            float s00 = Llo.y    + Rlo[c].y;
            float s01 = Llo.x    + Rhi.x;
            float s10 = Lhi[c].x + Rhi.x;
            float s11 = Llo.y    + Rhi.y;
            a1[c][0] = fmaf(tw1[0][0], s00, a1[c][0]);
            a1[c][0] = fmaf(tw1[1][0], s01, a1[c][0]);
            a1[c][1] = fmaf(tw1[0][1], s10, a1[c][1]);
            a1[c][1] = fmaf(tw1[1][1], s11, a1[c][1]);
            a2[c][0] = fmaf(tw2[0][0], s00, a2[c][0]);
            a2[c][0] = fmaf(tw2[1][0], s01, a2[c][0]);
            a2[c][1] = fmaf(tw2[0][1], s10, a2[c][1]);
            a2[c][1] = fmaf(tw2[1][1], s11, a2[c][1]);
            Lhi[c] = Llo; Rlo[c] = Rhi;
        }
    }

    {   // epilogue tap k = 31
        float t1e[2], t2e[2];
        #pragma unroll
        for (int p = 0; p < 2; ++p) {
            wv1[p] *= m1[p];
            float ta = (wv1[p] >= EPSW) ? wv1[p] : 0.f;
            t1e[p] = ta; S1[p] += ta;
            wv2[p] *= m2[p];
            float tb = (wv2[p] >= EPSW) ? wv2[p] : 0.f;
            t2e[p] = tb; S2[p] += tb;
        }
        const int li = 32 + w0 - 32;
        const int ri = 32 + w0 + 32;
        #pragma unroll
        for (int c = 0; c < 4; ++c) {
            float2 Lle = *(const float2*)&xs[c][li];
            float2 Rre = *(const float2*)&xs[c][ri];
            float s0 = Lle.y    + Rlo[c].y;
            float s1 = Lhi[c].x + Rre.x;
            a1[c][0] = fmaf(t1e[0], s0, a1[c][0]);
            a1[c][1] = fmaf(t1e[1], s1, a1[c][1]);
            a2[c][0] = fmaf(t2e[0], s0, a2[c][0]);
            a2[c][1] = fmaf(t2e[1], s1, a2[c][1]);
        }
    }

    float n1[2], n2[2];
    #pragma unroll
    for (int p = 0; p < 2; ++p) {
        n1[p] = 1.0f / (1.0f + 2.0f*S1[p] + 1e-8f);
        n2[p] = 1.0f / (1.0f + 2.0f*S2[p] + 1e-8f);
    }
    #pragma unroll
    for (int p = 0; p < 2; ++p) {
        uint4 pk;
        u32* pq = (u32*)&pk;
        #pragma unroll
        for (int c = 0; c < 4; ++c)
            pq[c] = (u32)f2bf(a1[c][p]*n1[p]) | ((u32)f2bf(a2[c][p]*n2[p]) << 16);
        size_t idx = ((size_t)(b*HH + h)*WW + (w0 + p))*CC + c0;
        *(uint4*)(ws + idx) = pk;
    }
}

// ---------------- vertical pass (MFMA): ws -> out (f32, g2-g1) --------------
// grid (64 wblk, 8 hblk, 4 b), block 512 = 8 waves. Per block: 8 w cols,
// 64 h out rows, all 32 ch, both gaussians. Wave wid owns column w = wid.
// out[c][h] = sum_r xin[c][r] * W[r][h] via mfma_f32_16x16x32_bf16:
//   M = 16 ch (x2 halves), N = 16 h (x4 tiles), K = 32 r (x4 K-tiles, 3 per htile).
__global__ __launch_bounds__(512)
void vpass(const u32* __restrict__ ws, const float* __restrict__ sig,
           float* __restrict__ out)
{
    __shared__ __align__(16) u16 Ag[8*32*128];   // 64KB: [w][c][r] granule-swizzled
    __shared__ float tt_l[2*8*64];
    __shared__ float si_l[2*8*64];

    const int t    = threadIdx.x;
    const int lane = t & 63;
    const int wid  = t >> 6;
    const int w0   = blockIdx.x * 8;
    const int h0   = blockIdx.y * 64;
    const int b    = blockIdx.z;

    // ---- prologue: tt and 1/S per (g, w, h)
    #pragma unroll
    for (int i = 0; i < 2; ++i) {
        int id = t + i*512;
        int wl = id & 7, h = (id >> 3) & 63, g = id >> 9;
        float s = sig[(size_t)(b*HH + h0 + h)*WW + w0 + wl];
        float tt = -0.5f / (s*s);
        if (g) tt *= 0.390625f;
        float S = 0.f;
        for (int k = 1; k <= 31; ++k) {
            float wf = __expf(tt * (float)(k*k));
            S += (wf >= EPSW) ? wf : 0.f;
        }
        tt_l[(g*8 + wl)*64 + h] = tt;
        si_l[(g*8 + wl)*64 + h] = 1.f / (1.f + 2.f*S + 1e-8f);
    }

    float acc0[4][2][4], acc1[4][2][4];   // [htile][chalf][reg]

    #pragma unroll 1
    for (int g = 0; g < 2; ++g) {
        __syncthreads();
        // ---- stage Ag[w][c][r] for this gaussian (r-pairs -> b32 writes)
        {
            const int c   = t & 31;
            const int grp = t >> 5;            // 0..15
            #pragma unroll
            for (int w8 = 0; w8 < 8; ++w8)
                #pragma unroll
                for (int rp = 0; rp < 4; ++rp) {
                    int r0  = (rp*16 + grp)*2;
                    int hh0 = reflect512(h0 - 32 + r0);
                    int hh1 = reflect512(h0 - 31 + r0);
                    u32 v0 = ws[((size_t)(b*HH + hh0)*WW + w0 + w8)*CC + c];
                    u32 v1 = ws[((size_t)(b*HH + hh1)*WW + w0 + w8)*CC + c];
                    u32 lo0 = g ? (v0 >> 16) : (v0 & 0xffffu);
                    u32 lo1 = g ? (v1 >> 16) : (v1 & 0xffffu);
                    int idx = ((w8*32 + c) << 7) + ((((r0 >> 3) ^ (c & 15))) << 3) + (r0 & 7);
                    *(u32*)&Ag[idx] = lo0 | (lo1 << 16);
                }
        }
        __syncthreads();

        // ---- A fragments: xin[c][r], lane: c = ch*16 + (lane&15), k = (lane>>4)*8+j
        FragU af[2][4];
        #pragma unroll
        for (int ch = 0; ch < 2; ++ch)
            #pragma unroll
            for (int kt = 0; kt < 4; ++kt) {
                int cc   = ch*16 + (lane & 15);
                int gran = kt*4 + (lane >> 4);
                int idx  = ((wid*32 + cc) << 7) + ((gran ^ (cc & 15)) << 3);
                af[ch][kt].s = *(const s16x8*)&Ag[idx];
            }

        // ---- per h-tile: build 3 B fragments (weights), 6 MFMA
        #pragma unroll
        for (int ht = 0; ht < 4; ++ht) {
            const int h_loc = ht*16 + (lane & 15);
            const float tt = tt_l[(g*8 + wid)*64 + h_loc];
            const int kbase = (ht < 2) ? 0 : 1;
            FragU bfr[3];
            #pragma unroll
            for (int kk = 0; kk < 3; ++kk) {
                int d0 = (kbase + kk)*32 + ((lane >> 4)*8) - h_loc - 32;
                #pragma unroll
                for (int j = 0; j < 8; ++j) {
                    int d = d0 + j;
                    float fd = (float)d;
                    float wf = __expf(tt * fd * fd);
                    bool ok = ((unsigned)(d + 31) <= 62u) && (wf >= EPSW);
                    float val = ok ? wf : 0.f;
                    bfr[kk].s[j] = (short)f2bf(val);
                }
            }
            float4 aL = make_float4(0.f, 0.f, 0.f, 0.f);
            float4 aH = make_float4(0.f, 0.f, 0.f, 0.f);
            typedef float f32x4 __attribute__((ext_vector_type(4)));
            f32x4 vL = {0.f,0.f,0.f,0.f}, vH = {0.f,0.f,0.f,0.f};
            #pragma unroll
            for (int kk = 0; kk < 3; ++kk) {
                vL = __builtin_amdgcn_mfma_f32_16x16x32_bf16(af[0][kbase+kk].b, bfr[kk].b, vL, 0, 0, 0);
                vH = __builtin_amdgcn_mfma_f32_16x16x32_bf16(af[1][kbase+kk].b, bfr[kk].b, vH, 0, 0, 0);
            }
            (void)aL; (void)aH;
            #pragma unroll
            for (int r = 0; r < 4; ++r) {
                if (g == 0) { acc0[ht][0][r] = vL[r]; acc0[ht][1][r] = vH[r]; }
                else        { acc1[ht][0][r] = vL[r]; acc1[ht][1][r] = vH[r]; }
            }
        }
    }

    // ---- normalize, subtract, transpose through LDS, store (two c-half phases)
    float* Dl = (float*)Ag;   // [16][64][9] f32, pitch-9 pad
    #pragma unroll
    for (int ch = 0; ch < 2; ++ch) {
        __syncthreads();
        #pragma unroll
        for (int ht = 0; ht < 4; ++ht) {
            const int h_loc = ht*16 + (lane & 15);
            float s0 = si_l[(0*8 + wid)*64 + h_loc];
            float s1 = si_l[(1*8 + wid)*64 + h_loc];
            #pragma unroll
            for (int r = 0; r < 4; ++r) {
                int c_loc = (lane >> 4)*4 + r;
                float v = acc1[ht][ch][r]*s1 - acc0[ht][ch][r]*s0;
                Dl[c_loc*576 + h_loc*9 + wid] = v;
            }
        }
        __syncthreads();
        #pragma unroll
        for (int r2 = 0; r2 < 2; ++r2) {
            int rid = t + r2*512;
            int c_loc = rid >> 6, h = rid & 63;
            float q[8];
            #pragma unroll
            for (int j = 0; j < 8; ++j) q[j] = Dl[c_loc*576 + h*9 + j];
            size_t gb = ((size_t)((b*CC + ch*16 + c_loc)*HH) + h0 + h)*WW + w0;
            *(float4*)(out + gb)     = make_float4(q[0], q[1], q[2], q[3]);
            *(float4*)(out + gb + 4) = make_float4(q[4], q[5], q[6], q[7]);
        }
    }
}

extern "C" void kernel_launch(void* const* d_in, const int* in_sizes, int n_in,
                              void* d_out, int out_size, void* d_ws, size_t ws_size,
                              hipStream_t stream) {
    const float* x   = (const float*)d_in[0];
    const float* sig = (const float*)d_in[1];
    float* out = (float*)d_out;

    const size_t n = (size_t)BB*CC*HH*WW;           // 33.55M px
    if (ws_size < n * sizeof(u32)) return;           // 134 MB interleaved bf16 pairs
    u32* ws = (u32*)d_ws;

    hpass<<<dim3(8, 512, 4), 256, 0, stream>>>(x, sig, ws);
    vpass<<<dim3(64, 8, 4), 512, 0, stream>>>(ws, sig, out);
}

// Round 5
// 609.864 us; speedup vs baseline: 1.0328x; 1.0328x over previous
//
#include <hip/hip_runtime.h>
#include <stdint.h>

typedef unsigned short u16;
typedef unsigned int   u32;

#define WW 512
#define HH 512
#define BB 4
#define CC 32
#define EPSW 1e-3f

typedef __bf16 bf16x8 __attribute__((ext_vector_type(8)));
typedef short  s16x8  __attribute__((ext_vector_type(8)));
typedef float  f32x4  __attribute__((ext_vector_type(4)));

union BU { u16 h[8]; u32 u[4]; bf16x8 b; s16x8 s; };

__device__ __forceinline__ int reflect512(int i) {
    i = (i < 0) ? -i : i;
    return (i >= WW) ? (2*WW - 2 - i) : i;
}
__device__ __forceinline__ u16 f2bf(float f) {
    u32 u = __float_as_uint(f);
    return (u16)((u + 0x7fffu + ((u >> 16) & 1u)) >> 16);
}

// ---------------- horizontal pass: x (f32) -> ws u32[b][h][w][c] {g1,g2} ----
// grid (8 wtiles, 512 h, 4 b), block 256. Thread: 4 ch x 2 w, both gaussians.
// Block covers ALL 32 c x 64 w -> stores assemble full 128B [w][c] records.
__global__ __launch_bounds__(256, 4)
void hpass(const float* __restrict__ x, const float* __restrict__ sig,
           u32* __restrict__ ws)
{
    __shared__ float xs[32*132];   // 32 ch x 128-w window (out 64 + 2x32 halo)
    const int t  = threadIdx.x;
    const int wt = blockIdx.x;
    const int h  = blockIdx.y;
    const int b  = blockIdx.z;
    const int wbase = wt*64 - 32;

    {   // stage: 32c x 128w reflected window
        const int wi = t & 127;
        const int gw = reflect512(wbase + wi);
        #pragma unroll
        for (int rep = 0; rep < 16; ++rep) {
            int c = rep*2 + (t >> 7);
            xs[c*132 + wi] = x[((size_t)((b*CC + c)*HH + h))*WW + gw];
        }
    }
    __syncthreads();

    const int c0  = (t & 7)*4;
    const int wp  = t >> 3;              // 0..31
    const int w0g = wt*64 + wp*2;
    const int bi0 = 32 + wp*2;

    float2 sg = *(const float2*)(sig + ((size_t)(b*HH + h))*WW + w0g);

    float m1[2], q1[2], wv1[2], S1[2], m2[2], q2[2], wv2[2], S2[2];
    #pragma unroll
    for (int p = 0; p < 2; ++p) {
        float s   = p ? sg.y : sg.x;
        float tt1 = -0.5f / (s*s);
        m1[p] = __expf(tt1);             q1[p] = m1[p]*m1[p];
        float tt2 = tt1 * 0.390625f;     // sigma2 = 1.6*sigma
        m2[p] = __expf(tt2);             q2[p] = m2[p]*m2[p];
        wv1[p] = 1.f; wv2[p] = 1.f; S1[p] = 0.f; S2[p] = 0.f;
    }

    float a1[4][2], a2[4][2];
    float2 Lhi[4], Rlo[4];
    #pragma unroll
    for (int c = 0; c < 4; ++c) {
        float2 Cq = *(const float2*)&xs[(c0+c)*132 + bi0];
        a1[c][0] = Cq.x; a1[c][1] = Cq.y;
        a2[c][0] = Cq.x; a2[c][1] = Cq.y;
        Lhi[c] = Cq; Rlo[c] = Cq;
    }

    #pragma unroll 1
    for (int kb = 0; kb < 15; ++kb) {      // taps k = 2kb+1, 2kb+2
        float tw1[2][2], tw2[2][2];
        #pragma unroll
        for (int j = 0; j < 2; ++j)
            #pragma unroll
            for (int p = 0; p < 2; ++p) {
                wv1[p] *= m1[p]; m1[p] *= q1[p];
                float ta = (wv1[p] >= EPSW) ? wv1[p] : 0.f;
                tw1[j][p] = ta; S1[p] += ta;
                wv2[p] *= m2[p]; m2[p] *= q2[p];
                float tb = (wv2[p] >= EPSW) ? wv2[p] : 0.f;
                tw2[j][p] = tb; S2[p] += tb;
            }
        const int li = bi0 - 2 - 2*kb;
        const int ri = bi0 + 2 + 2*kb;
        #pragma unroll
        for (int c = 0; c < 4; ++c) {
            float2 Llo = *(const float2*)&xs[(c0+c)*132 + li];
            float2 Rhi = *(const float2*)&xs[(c0+c)*132 + ri];
            float s00 = Llo.y    + Rlo[c].y;
            float s01 = Llo.x    + Rhi.x;
            float s10 = Lhi[c].x + Rhi.x;
            float s11 = Llo.y    + Rhi.y;
            a1[c][0] = fmaf(tw1[0][0], s00, a1[c][0]);
            a1[c][0] = fmaf(tw1[1][0], s01, a1[c][0]);
            a1[c][1] = fmaf(tw1[0][1], s10, a1[c][1]);
            a1[c][1] = fmaf(tw1[1][1], s11, a1[c][1]);
            a2[c][0] = fmaf(tw2[0][0], s00, a2[c][0]);
            a2[c][0] = fmaf(tw2[1][0], s01, a2[c][0]);
            a2[c][1] = fmaf(tw2[0][1], s10, a2[c][1]);
            a2[c][1] = fmaf(tw2[1][1], s11, a2[c][1]);
            Lhi[c] = Llo; Rlo[c] = Rhi;
        }
    }

    {   // epilogue tap k = 31
        float t1e[2], t2e[2];
        #pragma unroll
        for (int p = 0; p < 2; ++p) {
            wv1[p] *= m1[p];
            float ta = (wv1[p] >= EPSW) ? wv1[p] : 0.f;
            t1e[p] = ta; S1[p] += ta;
            wv2[p] *= m2[p];
            float tb = (wv2[p] >= EPSW) ? wv2[p] : 0.f;
            t2e[p] = tb; S2[p] += tb;
        }
        const int li = bi0 - 32;
        const int ri = bi0 + 32;
        #pragma unroll
        for (int c = 0; c < 4; ++c) {
            float2 Lle = *(const float2*)&xs[(c0+c)*132 + li];
            float2 Rre = *(const float2*)&xs[(c0+c)*132 + ri];
            float s0 = Lle.y    + Rlo[c].y;
            float s1 = Lhi[c].x + Rre.x;
            a1[c][0] = fmaf(t1e[0], s0, a1[c][0]);
            a1[c][1] = fmaf(t1e[1], s1, a1[c][1]);
            a2[c][0] = fmaf(t2e[0], s0, a2[c][0]);
            a2[c][1] = fmaf(t2e[1], s1, a2[c][1]);
        }
    }

    float n1[2], n2[2];
    #pragma unroll
    for (int p = 0; p < 2; ++p) {
        n1[p] = 1.0f / (1.0f + 2.0f*S1[p] + 1e-8f);
        n2[p] = 1.0f / (1.0f + 2.0f*S2[p] + 1e-8f);
    }
    #pragma unroll
    for (int p = 0; p < 2; ++p) {
        uint4 pk;
        u32* pq = (u32*)&pk;
        #pragma unroll
        for (int c = 0; c < 4; ++c)
            pq[c] = (u32)f2bf(a1[c][p]*n1[p]) | ((u32)f2bf(a2[c][p]*n2[p]) << 16);
        *(uint4*)(ws + ((size_t)(b*HH + h)*WW + (w0g + p))*CC + c0) = pk;
    }
}

// ---------------- vertical pass (MFMA): ws -> out (f32, g2-g1) --------------
// 1D grid 4096 (XCD-contiguous decode), block 256 = 4 waves. Tile: 4w x 64h
// x 32c, both g. Wave wid <-> w. Per g: stage 32KB bf16 LDS, per-element expf
// JIT weights packed via f2bf (R3-proven), MFMA 16x16x32, in-gen S + shfl.
__global__ __launch_bounds__(256, 4)
void vpass(const u32* __restrict__ ws, const float* __restrict__ sig,
           float* __restrict__ out)
{
    __shared__ float sb[8320];           // 33.3KB: As (32KB bf16) / Dl (f32) aliased
    u32* As4 = (u32*)sb;

    const int t    = threadIdx.x;
    const int lane = t & 63;
    const int wid  = t >> 6;             // 0..3
    const int l15  = lane & 15;
    const int grp  = lane >> 4;

    const int L    = blockIdx.x;
    const int nswz = (L & 7)*512 + (L >> 3);   // XCD-contiguous remap
    const int wblk = nswz & 127;
    const int hblk = (nswz >> 7) & 7;
    const int b    = nswz >> 10;
    const int w0   = wblk*4;
    const int h0   = hblk*64;

    float ttl[4];
    #pragma unroll
    for (int ht = 0; ht < 4; ++ht) {
        float s = sig[((size_t)(b*HH + h0 + ht*16 + l15))*WW + w0 + wid];
        ttl[ht] = -0.5f / (s*s);
    }

    f32x4 acc[2][4][2];
    #pragma unroll
    for (int g = 0; g < 2; ++g)
        #pragma unroll
        for (int ht = 0; ht < 4; ++ht)
            #pragma unroll
            for (int ch = 0; ch < 2; ++ch)
                acc[g][ht][ch] = (f32x4){0.f, 0.f, 0.f, 0.f};

    const int c32 = t & 31;
    const int rp  = t >> 5;              // 0..7

    #pragma unroll
    for (int g = 0; g < 2; ++g) {
        if (g) __syncthreads();          // previous compute done before restage
        // ---- stage this gaussian's bf16 half: As[w][c][r] swizzled
        #pragma unroll
        for (int k = 0; k < 8; ++k) {
            int r0  = rp*2 + k*16;       // even rows 0..126
            int hh0 = reflect512(h0 - 32 + r0);
            int hh1 = reflect512(h0 - 31 + r0);
            size_t ga = ((size_t)(b*HH + hh0))*WW;
            size_t gb = ((size_t)(b*HH + hh1))*WW;
            #pragma unroll
            for (int w = 0; w < 4; ++w) {
                u32 va = ws[(ga + w0 + w)*CC + c32];
                u32 vb = ws[(gb + w0 + w)*CC + c32];
                u32 pk = g ? ((va >> 16) | (vb & 0xffff0000u))
                           : ((va & 0xffffu) | (vb << 16));
                int idx = (w*32 + c32)*64 + (((r0 >> 3) ^ (c32 & 7)) << 2) + ((r0 >> 1) & 3);
                As4[idx] = pk;
            }
        }
        __syncthreads();

        // ---- A fragment preload (R3 pattern): af[ch][kt]
        BU af[2][4];
        #pragma unroll
        for (int ch = 0; ch < 2; ++ch)
            #pragma unroll
            for (int kt = 0; kt < 4; ++kt) {
                int cc = ch*16 + l15;
                af[ch][kt].s = *(const s16x8*)&As4[(wid*32 + cc)*64 + (((kt*4 + grp) ^ (l15 & 7)) << 2)];
            }

        // ---- per h-tile: JIT weights (expf + f2bf), S in-gen, 6 MFMA
        #pragma unroll
        for (int ht = 0; ht < 4; ++ht) {
            const int   kbase = ht >> 1;
            const float tt    = ttl[ht] * (g ? 0.390625f : 1.0f);
            const int   hl    = ht*16 + l15;
            float S = 0.f;
            #pragma unroll
            for (int kk = 0; kk < 3; ++kk) {
                const int kt = kbase + kk;
                const int d0 = kt*32 + grp*8 - hl - 32;
                BU bfr;
                #pragma unroll
                for (int j = 0; j < 8; ++j) {
                    int d = d0 + j;
                    float wf = __expf(tt * (float)(d*d));
                    bool ok = ((u32)(d + 31) <= 62u) && (wf >= EPSW);
                    float val = ok ? wf : 0.f;
                    S += val;
                    bfr.h[j] = f2bf(val);
                }
                acc[g][ht][0] = __builtin_amdgcn_mfma_f32_16x16x32_bf16(af[0][kt].b, bfr.b, acc[g][ht][0], 0, 0, 0);
                acc[g][ht][1] = __builtin_amdgcn_mfma_f32_16x16x32_bf16(af[1][kt].b, bfr.b, acc[g][ht][1], 0, 0, 0);
            }
            S += __shfl_xor(S, 16);
            S += __shfl_xor(S, 32);
            float nrm = 1.0f / (S + 1e-8f);
            #pragma unroll
            for (int ch = 0; ch < 2; ++ch)
                #pragma unroll
                for (int r = 0; r < 4; ++r)
                    acc[g][ht][ch][r] *= nrm;
        }
    }

    // ---- epilogue: diff, transpose through LDS (Dl[(c*4+w)][65]), store
    __syncthreads();
    #pragma unroll
    for (int ht = 0; ht < 4; ++ht)
        #pragma unroll
        for (int ch = 0; ch < 2; ++ch)
            #pragma unroll
            for (int r = 0; r < 4; ++r) {
                int c  = ch*16 + grp*4 + r;
                int hh = ht*16 + l15;
                sb[(c*4 + wid)*65 + hh] = acc[1][ht][ch][r] - acc[0][ht][ch][r];
            }
    __syncthreads();
    {
        const int c  = t & 31;
        const int h8 = t >> 5;
        #pragma unroll
        for (int hi = 0; hi < 8; ++hi) {
            int hh = h8*8 + hi;
            float4 q;
            q.x = sb[(c*4 + 0)*65 + hh];
            q.y = sb[(c*4 + 1)*65 + hh];
            q.z = sb[(c*4 + 2)*65 + hh];
            q.w = sb[(c*4 + 3)*65 + hh];
            *(float4*)(out + ((size_t)((b*CC + c)*HH + h0 + hh))*WW + w0) = q;
        }
    }
}

extern "C" void kernel_launch(void* const* d_in, const int* in_sizes, int n_in,
                              void* d_out, int out_size, void* d_ws, size_t ws_size,
                              hipStream_t stream) {
    const float* x   = (const float*)d_in[0];
    const float* sig = (const float*)d_in[1];
    float* out = (float*)d_out;

    const size_t n = (size_t)BB*CC*HH*WW;           // 33.55M px
    if (ws_size < n * sizeof(u32)) return;           // 134 MB interleaved bf16 pairs
    u32* ws = (u32*)d_ws;

    hpass<<<dim3(8, 512, 4), 256, 0, stream>>>(x, sig, ws);
    vpass<<<dim3(4096), 256, 0, stream>>>(ws, sig, out);
}